// Round 9
// baseline (715.718 us; speedup 1.0000x reference)
//
#include <hip/hip_runtime.h>

#define DD 1024

typedef int   i32x4  __attribute__((ext_vector_type(4)));
typedef int   i32x8  __attribute__((ext_vector_type(8)));
typedef float f32x4  __attribute__((ext_vector_type(4)));

__device__ __forceinline__ float sigm(float x) { return 1.0f / (1.0f + __expf(-x)); }
__device__ __forceinline__ float tanh_fast(float x) {
  float e = __expf(-2.0f * fabsf(x));
  float t = (1.0f - e) / (1.0f + e);
  return copysignf(t, x);
}
__device__ __forceinline__ void gload_lds16(const void* g, void* l) {
  __builtin_amdgcn_global_load_lds((const __attribute__((address_space(1))) void*)g,
                                   (__attribute__((address_space(3))) void*)l, 16, 0, 0);
}
__device__ __forceinline__ unsigned pk_fp8x4(float a, float b, float c, float d) {
  int u = __builtin_amdgcn_cvt_pk_fp8_f32(a, b, 0, false);
  u = __builtin_amdgcn_cvt_pk_fp8_f32(c, d, u, true);
  return (unsigned)u;
}

// ---- one-time weight prep: Wcat8[4][1024][1024] fp8(e4m3, W*32), bias[4][1024] f32
// g=0: Wih_r+Whh_r ; g=1: Wih_z+Whh_z ; g=2: Wih_n ; g=3: Whh_n
__global__ __launch_bounds__(256) void prep_weights(
    const float* __restrict__ Wih, const float* __restrict__ Whh,
    const float* __restrict__ bih, const float* __restrict__ bhh,
    unsigned char* __restrict__ Wcat8, float* __restrict__ bias) {
  int i = blockIdx.x * 256 + threadIdx.x;   // 4-elem units over 4*D*D/4
  int g = i >> 18;
  int rem = i & 262143;
  int n = rem >> 8;
  int k4 = rem & 255;
  const float4* wih4 = reinterpret_cast<const float4*>(Wih);
  const float4* whh4 = reinterpret_cast<const float4*>(Whh);
  float4 v;
  if (g == 0) {
    size_t idx = (size_t)n * 256 + k4;
    float4 a = wih4[idx], b = whh4[idx];
    v = make_float4(a.x + b.x, a.y + b.y, a.z + b.z, a.w + b.w);
  } else if (g == 1) {
    size_t idx = (size_t)(DD + n) * 256 + k4;
    float4 a = wih4[idx], b = whh4[idx];
    v = make_float4(a.x + b.x, a.y + b.y, a.z + b.z, a.w + b.w);
  } else if (g == 2) {
    size_t idx = (size_t)(2 * DD + n) * 256 + k4;
    v = wih4[idx];
  } else {
    size_t idx = (size_t)(2 * DD + n) * 256 + k4;
    v = whh4[idx];
  }
  // scale x32 (exact) so weights leave the e4m3 denormal zone; MX B-scale 2^-5 undoes it
  reinterpret_cast<unsigned*>(Wcat8)[i] =
      pk_fp8x4(v.x * 32.0f, v.y * 32.0f, v.z * 32.0f, v.w * 32.0f);

  if (i < 4 * DD) {
    int bg = i >> 10, bn = i & 1023;
    float bv;
    if (bg == 0)      bv = bih[bn] + bhh[bn];
    else if (bg == 1) bv = bih[DD + bn] + bhh[DD + bn];
    else if (bg == 2) bv = bih[2 * DD + bn];
    else              bv = bhh[2 * DD + bn];
    bias[i] = bv;
  }
}

// ---- per-iteration: error GEMV + fp8 cast of state (single read of state) ----
__global__ __launch_bounds__(256) void error_cast(
    const float* S, const float* __restrict__ We, const float* __restrict__ be,
    unsigned char* __restrict__ Sb8, float* __restrict__ err) {
  __shared__ float part[4];
  const int row = blockIdx.x;
  const int t = threadIdx.x;
  float4 v = reinterpret_cast<const float4*>(S + (size_t)row * DD)[t];
  float4 w = reinterpret_cast<const float4*>(We)[t];
  float dot = v.x * w.x + v.y * w.y + v.z * w.z + v.w * w.w;
  reinterpret_cast<unsigned*>(Sb8 + (size_t)row * DD)[t] = pk_fp8x4(v.x, v.y, v.z, v.w);
#pragma unroll
  for (int off = 32; off > 0; off >>= 1) dot += __shfl_xor(dot, off);
  if ((t & 63) == 0) part[t >> 6] = dot;
  __syncthreads();
  if (t == 0) err[row] = sigm(part[0] + part[1] + part[2] + part[3] + be[0]);
}

// ---- fused 4-gate MX-fp8 GEMM + GRU epilogue ----
// Tile 128M x 128N(4g x 32dg), BK=128, 8 K-tiles, 4 waves (2M x 2N), wave 64x64.
// mfma_scale_f32_16x16x128_f8f6f4: 16 MFMA : 16 ds_read_b128 per wave per tile.
// LDS SUBTILE layout (row-driven banks, the empirically conflict-free pattern):
//   tile = 16 subtiles of [8 granules][8 rows][16B]; addr(r,c) = (r>>3)*1024
//   + c*128 + (r&7)*16. Staging stays linear (lane l -> row 8j+(l&7), gran l>>3,
//   per-lane transposed global source covering 8 full 128B lines per instr).
// XCD decode: each XCD owns 16db x 64rb, db-fast -> L2 set = 4 A-blk + 16 B-panels.
__global__ __launch_bounds__(256, 2) void gru_fused_gemm(
    const unsigned char* __restrict__ Sb8,   // [M][1024] fp8 state
    const unsigned char* __restrict__ Wcat8, // [4096][1024] fp8 (W*32)
    const float* __restrict__ bias,          // [4096]
    const float* __restrict__ err,           // [M]
    const float* Sf,                         // [M][1024] f32 h (may alias out)
    float* out, int M) {
  __shared__ alignas(16) unsigned char As[2 * 16384];   // 32 KB
  __shared__ alignas(16) unsigned char Bs[2 * 16384];   // 32 KB

  // two-level XCD decode: xcd -> (db half, rb quarter); within: db fast
  const int bid = blockIdx.x;
  const int x = bid & 7;
  const int c = bid >> 3;                  // 0..1023
  const int db = (x & 1) * 16 + (c & 15);  // 0..31
  const int rb = (x >> 1) * 64 + (c >> 4); // 0..255

  const int tid = threadIdx.x;
  const int w = tid >> 6;                  // 0..3
  const int lane = tid & 63;
  const int l15 = lane & 15;
  const int q = lane >> 4;                 // 0..3
  const int wr = w >> 1, wc = w & 1;

  // ---- staging: 32 x 1KB instrs (16 A + 16 B); wave w: instrs w+4i.
  // instr j = subtile j: lane l -> row 8j+(l&7), granule l>>3 (linear LDS dst).
  const int r7 = lane & 7;
  const int gp = lane >> 3;
  const unsigned char* srcA[4];
  const unsigned char* srcB[4];
  unsigned char* dstA[4];
  unsigned char* dstB[4];
#pragma unroll
  for (int i = 0; i < 4; ++i) {
    int j = w + i * 4;
    int row = j * 8 + r7;                  // 0..127
    srcA[i] = Sb8 + (size_t)(rb * 128 + row) * DD + gp * 16;
    // n_t bits: [6]=wc, [5:4]=gate, [3:0]=dgl low ; dgl = (n_t&15) + (n_t>>6)*16
    int gate = (row >> 4) & 3;
    int dgl = (row & 15) + (row >> 6) * 16;
    srcB[i] = Wcat8 + (size_t)(gate * DD + db * 32 + dgl) * DD + gp * 16;
    dstA[i] = As + j * 1024;
    dstB[i] = Bs + j * 1024;
  }

  // ---- frag read offsets: (sub)*1024 + gran*128 + (row&7)*16
  // A row = wr*64 + mi*16 + l15 ; gran = 2q (+s). mi -> +2048, s -> +128.
  const int abase = (wr * 8 + (l15 >> 3)) * 1024 + 2 * q * 128 + (l15 & 7) * 16;
  const int bbase = (wc * 8 + (l15 >> 3)) * 1024 + 2 * q * 128 + (l15 & 7) * 16;

  f32x4 acc[4][4];
#pragma unroll
  for (int mi = 0; mi < 4; ++mi)
#pragma unroll
    for (int g = 0; g < 4; ++g) acc[mi][g] = f32x4{0.f, 0.f, 0.f, 0.f};

  auto stage = [&](int t) {
    const int slot = (t & 1) * 16384;
    const int koff = t * 128;
#pragma unroll
    for (int i = 0; i < 4; ++i) {
      gload_lds16(srcA[i] + koff, dstA[i] + slot);
      gload_lds16(srcB[i] + koff, dstB[i] + slot);
    }
  };

  stage(0);
  stage(1);

  for (int t = 0; t < 8; ++t) {
    const int sb = (t & 1) * 16384;
    if (t < 7) asm volatile("s_waitcnt vmcnt(8)" ::: "memory");
    else       asm volatile("s_waitcnt vmcnt(0)" ::: "memory");
    __builtin_amdgcn_s_barrier();

    const unsigned char* Ab = As + sb;
    const unsigned char* Bb = Bs + sb;
    i32x8 a[4], b[4];
#pragma unroll
    for (int mi = 0; mi < 4; ++mi) {
      i32x4 a0 = *reinterpret_cast<const i32x4*>(Ab + abase + mi * 2048);
      i32x4 a1 = *reinterpret_cast<const i32x4*>(Ab + abase + mi * 2048 + 128);
      a[mi] = __builtin_shufflevector(a0, a1, 0, 1, 2, 3, 4, 5, 6, 7);
    }
#pragma unroll
    for (int g = 0; g < 4; ++g) {
      i32x4 b0 = *reinterpret_cast<const i32x4*>(Bb + bbase + g * 2048);
      i32x4 b1 = *reinterpret_cast<const i32x4*>(Bb + bbase + g * 2048 + 128);
      b[g] = __builtin_shufflevector(b0, b1, 0, 1, 2, 3, 4, 5, 6, 7);
    }
    asm volatile("s_waitcnt lgkmcnt(0)" ::: "memory");
    __builtin_amdgcn_s_barrier();               // slot sb free block-wide

    if (t <= 5) stage(t + 2);                   // into freed slot sb

    __builtin_amdgcn_s_setprio(1);
#pragma unroll
    for (int g = 0; g < 4; ++g)
#pragma unroll
      for (int mi = 0; mi < 4; ++mi)
        acc[mi][g] = __builtin_amdgcn_mfma_scale_f32_16x16x128_f8f6f4(
            a[mi], b[g], acc[mi][g], 0, 0, 0, 0x7F7F7F7F, 0, 0x7A7A7A7A);
    __builtin_amdgcn_s_setprio(0);
  }

  // ---- epilogue: r,z,n + out = h + e*(1-z)*(n-h)
  // C/D 16x16 layout: col = lane&15 (N), row = q*4 + reg (M)
  const int dgcol = db * 32 + wc * 16 + l15;
  const float b_r = bias[dgcol];
  const float b_z = bias[DD + dgcol];
  const float b_i = bias[2 * DD + dgcol];
  const float b_h = bias[3 * DD + dgcol];
#pragma unroll
  for (int mi = 0; mi < 4; ++mi) {
#pragma unroll
    for (int j = 0; j < 4; ++j) {
      int m = rb * 128 + wr * 64 + mi * 16 + q * 4 + j;
      float e = err[m];
      float hh = Sf[(size_t)m * DD + dgcol];
      float r = sigm(acc[mi][0][j] + b_r);
      float z = sigm(acc[mi][1][j] + b_z);
      float n = tanh_fast(acc[mi][2][j] + b_i + r * (acc[mi][3][j] + b_h));
      out[(size_t)m * DD + dgcol] = hh + e * (1.0f - z) * (n - hh);
    }
  }
}

extern "C" void kernel_launch(void* const* d_in, const int* in_sizes, int n_in,
                              void* d_out, int out_size, void* d_ws, size_t ws_size,
                              hipStream_t stream) {
  const float* x   = (const float*)d_in[0];
  const float* Wih = (const float*)d_in[1];
  const float* Whh = (const float*)d_in[2];
  const float* bih = (const float*)d_in[3];
  const float* bhh = (const float*)d_in[4];
  const float* We  = (const float*)d_in[5];
  const float* be  = (const float*)d_in[6];
  float* out = (float*)d_out;
  const int M = in_sizes[0] / DD;   // 32768

  char* ws = (char*)d_ws;
  unsigned char* Sb8   = (unsigned char*)ws;                         // M*D = 32 MB
  unsigned char* Wcat8 = (unsigned char*)(ws + (size_t)M * DD);      // 4 MB
  float* bias = (float*)(ws + (size_t)M * DD + (size_t)4 * DD * DD);
  float* err  = (float*)(ws + (size_t)M * DD + (size_t)4 * DD * DD + (size_t)4 * DD * 4);

  prep_weights<<<4096, 256, 0, stream>>>(Wih, Whh, bih, bhh, Wcat8, bias);

  const int nwg = (M / 128) * 32;   // 8192
  const float* S = x;
  for (int it = 0; it < 2; ++it) {
    error_cast<<<M, 256, 0, stream>>>(S, We, be, Sb8, err);
    gru_fused_gemm<<<nwg, 256, 0, stream>>>(Sb8, Wcat8, bias, err, S, out, M);
    S = out;
  }
}

// Round 10
// 525.284 us; speedup vs baseline: 1.3625x; 1.3625x over previous
//
#include <hip/hip_runtime.h>

#define DD 1024

typedef int   i32x4  __attribute__((ext_vector_type(4)));
typedef int   i32x8  __attribute__((ext_vector_type(8)));
typedef float f32x4  __attribute__((ext_vector_type(4)));

__device__ __forceinline__ float sigm(float x) { return 1.0f / (1.0f + __expf(-x)); }
__device__ __forceinline__ float tanh_fast(float x) {
  float e = __expf(-2.0f * fabsf(x));
  float t = (1.0f - e) / (1.0f + e);
  return copysignf(t, x);
}
__device__ __forceinline__ void gload_lds16(const void* g, void* l) {
  __builtin_amdgcn_global_load_lds((const __attribute__((address_space(1))) void*)g,
                                   (__attribute__((address_space(3))) void*)l, 16, 0, 0);
}
__device__ __forceinline__ unsigned pk_fp8x4(float a, float b, float c, float d) {
  int u = __builtin_amdgcn_cvt_pk_fp8_f32(a, b, 0, false);
  u = __builtin_amdgcn_cvt_pk_fp8_f32(c, d, u, true);
  return (unsigned)u;
}

// Tile image (16 KB per (128-row, 128-k) tile): addr(r, k) =
//   (k>>7)*16384 + (r>>3)*1024 + ((k>>4)&7)*128 + (r&7)*16 + (k&15)
// A image: rb-major, 131072 B per rb. B image: db-major, 131072 B per db,
// with B row n_t = wc*64 + gate*16 + dgl_lo  (wc = dgl>>4).

// ---- one-time weight prep: Wcat8 tiled image, bias[4][1024] f32 ----
// g=0: Wih_r+Whh_r ; g=1: Wih_z+Whh_z ; g=2: Wih_n ; g=3: Whh_n
__global__ __launch_bounds__(256) void prep_weights(
    const float* __restrict__ Wih, const float* __restrict__ Whh,
    const float* __restrict__ bih, const float* __restrict__ bhh,
    unsigned char* __restrict__ Wcat8, float* __restrict__ bias) {
  int i = blockIdx.x * 256 + threadIdx.x;   // 4-elem units over 4*D*D/4
  int g = i >> 18;
  int rem = i & 262143;
  int n = rem >> 8;
  int k4 = rem & 255;
  const float4* wih4 = reinterpret_cast<const float4*>(Wih);
  const float4* whh4 = reinterpret_cast<const float4*>(Whh);
  float4 v;
  if (g == 0) {
    size_t idx = (size_t)n * 256 + k4;
    float4 a = wih4[idx], b = whh4[idx];
    v = make_float4(a.x + b.x, a.y + b.y, a.z + b.z, a.w + b.w);
  } else if (g == 1) {
    size_t idx = (size_t)(DD + n) * 256 + k4;
    float4 a = wih4[idx], b = whh4[idx];
    v = make_float4(a.x + b.x, a.y + b.y, a.z + b.z, a.w + b.w);
  } else if (g == 2) {
    size_t idx = (size_t)(2 * DD + n) * 256 + k4;
    v = wih4[idx];
  } else {
    size_t idx = (size_t)(2 * DD + n) * 256 + k4;
    v = whh4[idx];
  }
  // scale x32 (exact) so weights leave the e4m3 denormal zone; MX B-scale 2^-5 undoes it
  unsigned pkd = pk_fp8x4(v.x * 32.0f, v.y * 32.0f, v.z * 32.0f, v.w * 32.0f);

  // tiled B address for (gate g, weight-col n, k = 4*k4)
  int db  = n >> 5;
  int dgl = n & 31;
  int n_t = (dgl >> 4) * 64 + g * 16 + (dgl & 15);
  int kt   = k4 >> 5;
  int gran = (k4 >> 2) & 7;
  int klo  = (k4 & 3) * 4;
  size_t addr = (size_t)db * 131072 + kt * 16384 + (n_t >> 3) * 1024 +
                gran * 128 + (n_t & 7) * 16 + klo;
  *reinterpret_cast<unsigned*>(Wcat8 + addr) = pkd;

  if (i < 4 * DD) {
    int bg = i >> 10, bn = i & 1023;
    float bv;
    if (bg == 0)      bv = bih[bn] + bhh[bn];
    else if (bg == 1) bv = bih[DD + bn] + bhh[DD + bn];
    else if (bg == 2) bv = bih[2 * DD + bn];
    else              bv = bhh[2 * DD + bn];
    bias[i] = bv;
  }
}

// ---- per-iteration: error GEMV + fp8 cast of state into tiled A image ----
__global__ __launch_bounds__(256) void error_cast(
    const float* S, const float* __restrict__ We, const float* __restrict__ be,
    unsigned char* __restrict__ Sb8, float* __restrict__ err) {
  __shared__ float part[4];
  const int row = blockIdx.x;
  const int t = threadIdx.x;
  float4 v = reinterpret_cast<const float4*>(S + (size_t)row * DD)[t];
  float4 w = reinterpret_cast<const float4*>(We)[t];
  float dot = v.x * w.x + v.y * w.y + v.z * w.z + v.w * w.w;

  // tiled A address for (row, k = 4t)
  int kt   = t >> 5;
  int gran = (t >> 2) & 7;
  int klo  = (t & 3) * 4;
  int r    = row & 127;
  size_t addr = (size_t)(row >> 7) * 131072 + kt * 16384 + (r >> 3) * 1024 +
                gran * 128 + (r & 7) * 16 + klo;
  *reinterpret_cast<unsigned*>(Sb8 + addr) = pk_fp8x4(v.x, v.y, v.z, v.w);

#pragma unroll
  for (int off = 32; off > 0; off >>= 1) dot += __shfl_xor(dot, off);
  if ((t & 63) == 0) part[t >> 6] = dot;
  __syncthreads();
  if (t == 0) err[row] = sigm(part[0] + part[1] + part[2] + part[3] + be[0]);
}

// ---- fused 4-gate MX-fp8 GEMM + GRU epilogue ----
// Tile 128M x 128N(4g x 32dg), BK=128, 8 K-tiles, 4 waves (2M x 2N), wave 64x64.
// mfma_scale_f32_16x16x128_f8f6f4. Operands pre-swizzled in global to the LDS
// tile image -> staging is a pure linear copy (1 KB consecutive per instr,
// lane-adjacent: maximal coalescing) AND subtile LDS layout for reads.
// XCD decode: xcd owns 16db x 64rb, db fast -> L2 set = 4 A-blk + 16 B-panels.
__global__ __launch_bounds__(256, 2) void gru_fused_gemm(
    const unsigned char* __restrict__ Sb8,   // tiled A image
    const unsigned char* __restrict__ Wcat8, // tiled B image
    const float* __restrict__ bias,          // [4096]
    const float* __restrict__ err,           // [M]
    const float* Sf,                         // [M][1024] f32 h (may alias out)
    float* out, int M) {
  __shared__ alignas(16) unsigned char As[2 * 16384];   // 32 KB
  __shared__ alignas(16) unsigned char Bs[2 * 16384];   // 32 KB

  // two-level XCD decode: xcd -> (db half, rb quarter); within: db fast
  const int bid = blockIdx.x;
  const int x = bid & 7;
  const int c = bid >> 3;                  // 0..1023
  const int db = (x & 1) * 16 + (c & 15);  // 0..31
  const int rb = (x >> 1) * 64 + (c >> 4); // 0..255

  const int tid = threadIdx.x;
  const int w = tid >> 6;                  // 0..3
  const int lane = tid & 63;
  const int l15 = lane & 15;
  const int q = lane >> 4;                 // 0..3
  const int wr = w >> 1, wc = w & 1;

  // ---- staging: pure linear copy; wave w stages chunks j = w+4i (1 KB each)
  const unsigned char* srcA0 = Sb8 + (size_t)rb * 131072 + lane * 16;
  const unsigned char* srcB0 = Wcat8 + (size_t)db * 131072 + lane * 16;

  // ---- frag read offsets: (sub)*1024 + gran*128 + (row&7)*16
  const int abase = (wr * 8 + (l15 >> 3)) * 1024 + 2 * q * 128 + (l15 & 7) * 16;
  const int bbase = (wc * 8 + (l15 >> 3)) * 1024 + 2 * q * 128 + (l15 & 7) * 16;

  f32x4 acc[4][4];
#pragma unroll
  for (int mi = 0; mi < 4; ++mi)
#pragma unroll
    for (int g = 0; g < 4; ++g) acc[mi][g] = f32x4{0.f, 0.f, 0.f, 0.f};

  auto stage = [&](int t) {
    const int slot = (t & 1) * 16384;
    const int koff = t * 16384;
#pragma unroll
    for (int i = 0; i < 4; ++i) {
      const int j = (w + i * 4) * 1024;
      gload_lds16(srcA0 + koff + j, As + j + slot);
      gload_lds16(srcB0 + koff + j, Bs + j + slot);
    }
  };

  stage(0);
  stage(1);

  for (int t = 0; t < 8; ++t) {
    const int sb = (t & 1) * 16384;
    if (t < 7) asm volatile("s_waitcnt vmcnt(8)" ::: "memory");
    else       asm volatile("s_waitcnt vmcnt(0)" ::: "memory");
    __builtin_amdgcn_s_barrier();

    const unsigned char* Ab = As + sb;
    const unsigned char* Bb = Bs + sb;
    i32x8 a[4], b[4];
#pragma unroll
    for (int mi = 0; mi < 4; ++mi) {
      i32x4 a0 = *reinterpret_cast<const i32x4*>(Ab + abase + mi * 2048);
      i32x4 a1 = *reinterpret_cast<const i32x4*>(Ab + abase + mi * 2048 + 128);
      a[mi] = __builtin_shufflevector(a0, a1, 0, 1, 2, 3, 4, 5, 6, 7);
    }
#pragma unroll
    for (int g = 0; g < 4; ++g) {
      i32x4 b0 = *reinterpret_cast<const i32x4*>(Bb + bbase + g * 2048);
      i32x4 b1 = *reinterpret_cast<const i32x4*>(Bb + bbase + g * 2048 + 128);
      b[g] = __builtin_shufflevector(b0, b1, 0, 1, 2, 3, 4, 5, 6, 7);
    }
    asm volatile("s_waitcnt lgkmcnt(0)" ::: "memory");
    __builtin_amdgcn_s_barrier();               // slot sb free block-wide

    if (t <= 5) stage(t + 2);                   // into freed slot sb

    __builtin_amdgcn_s_setprio(1);
#pragma unroll
    for (int g = 0; g < 4; ++g)
#pragma unroll
      for (int mi = 0; mi < 4; ++mi)
        acc[mi][g] = __builtin_amdgcn_mfma_scale_f32_16x16x128_f8f6f4(
            a[mi], b[g], acc[mi][g], 0, 0, 0, 0x7F7F7F7F, 0, 0x7A7A7A7A);
    __builtin_amdgcn_s_setprio(0);
  }

  // ---- epilogue: r,z,n + out = h + e*(1-z)*(n-h)
  // C/D 16x16 layout: col = lane&15 (N), row = q*4 + reg (M)
  const int dgcol = db * 32 + wc * 16 + l15;
  const float b_r = bias[dgcol];
  const float b_z = bias[DD + dgcol];
  const float b_i = bias[2 * DD + dgcol];
  const float b_h = bias[3 * DD + dgcol];
#pragma unroll
  for (int mi = 0; mi < 4; ++mi) {
#pragma unroll
    for (int j = 0; j < 4; ++j) {
      int m = rb * 128 + wr * 64 + mi * 16 + q * 4 + j;
      float e = err[m];
      float hh = Sf[(size_t)m * DD + dgcol];
      float r = sigm(acc[mi][0][j] + b_r);
      float z = sigm(acc[mi][1][j] + b_z);
      float n = tanh_fast(acc[mi][2][j] + b_i + r * (acc[mi][3][j] + b_h));
      out[(size_t)m * DD + dgcol] = hh + e * (1.0f - z) * (n - hh);
    }
  }
}

extern "C" void kernel_launch(void* const* d_in, const int* in_sizes, int n_in,
                              void* d_out, int out_size, void* d_ws, size_t ws_size,
                              hipStream_t stream) {
  const float* x   = (const float*)d_in[0];
  const float* Wih = (const float*)d_in[1];
  const float* Whh = (const float*)d_in[2];
  const float* bih = (const float*)d_in[3];
  const float* bhh = (const float*)d_in[4];
  const float* We  = (const float*)d_in[5];
  const float* be  = (const float*)d_in[6];
  float* out = (float*)d_out;
  const int M = in_sizes[0] / DD;   // 32768

  char* ws = (char*)d_ws;
  unsigned char* Sb8   = (unsigned char*)ws;                         // M*D = 32 MB (tiled)
  unsigned char* Wcat8 = (unsigned char*)(ws + (size_t)M * DD);      // 4 MB (tiled)
  float* bias = (float*)(ws + (size_t)M * DD + (size_t)4 * DD * DD);
  float* err  = (float*)(ws + (size_t)M * DD + (size_t)4 * DD * DD + (size_t)4 * DD * 4);

  prep_weights<<<4096, 256, 0, stream>>>(Wih, Whh, bih, bhh, Wcat8, bias);

  const int nwg = (M / 128) * 32;   // 8192
  const float* S = x;
  for (int it = 0; it < 2; ++it) {
    error_cast<<<M, 256, 0, stream>>>(S, We, be, Sb8, err);
    gru_fused_gemm<<<nwg, 256, 0, stream>>>(Sb8, Wcat8, bias, err, S, out, M);
    S = out;
  }
}